// Round 6
// baseline (526.407 us; speedup 1.0000x reference)
//
#include <hip/hip_runtime.h>
#include <cstddef>

// Problem dims
#define TT 65536
#define NK (TT - 1)      // scan steps
#define NCH 512          // chunks
#define CLEN 128         // chunk length
#define SUBL 32          // sub-chain length inside k_chunk (CLEN/4)

// d_out offsets (floats): log_alpha, log_beta, log_trs, log_pis, entropy
#define OFF_ALPHA 0
#define OFF_BETA  (TT * 16)
#define OFF_TRS   (2 * TT * 16)
#define OFF_PIS   (OFF_TRS + NK * 256)
#define OFF_ENT   (OFF_PIS + TT * 16)

// bf16 weight plane element offsets (ushort units), layout [n][k]
#define W_PW1 0        // 256 x 64
#define W_PW2 16384    // 256 x 256
#define W_PW3 81920    // 128 x 256
#define W_OW1 114688   // 256 x 64
#define W_OW2 131072   // 256 x 256
#define W_OW3 196608   // 272 x 256 (rows 256..271 unused by MFMA path)
#define W_TOTAL 266240
#define WS_WEIGHT_OFF 589888   // bytes: scan float region sits below this

typedef __attribute__((ext_vector_type(8))) short bf16x8;
typedef __attribute__((ext_vector_type(4))) float f32x4;
typedef __attribute__((ext_vector_type(4))) unsigned short us4;

__device__ __forceinline__ unsigned short bf16_rne(float x) {
  unsigned int u = __float_as_uint(x);
  unsigned int r = u + 0x7FFFu + ((u >> 16) & 1u);
  return (unsigned short)(r >> 16);
}
__device__ __forceinline__ float bf16_f(unsigned short h) {
  return __uint_as_float(((unsigned int)h) << 16);
}

__device__ __forceinline__ void lse_merge(float& m, float& s, float mo, float so) {
  float mm = fmaxf(m, mo);
  s = s * __expf(m - mm) + so * __expf(mo - mm);
  m = mm;
}

// ---------------- Kernel 0: weight convert fp32 -> bf16 hi plane, [n][k] ----------------
extern "C" __global__ void __launch_bounds__(256)
k_wconv(const float* __restrict__ pW1, const float* __restrict__ pW2,
        const float* __restrict__ pW3, const float* __restrict__ oW1,
        const float* __restrict__ oW2, const float* __restrict__ oW3,
        unsigned short* __restrict__ wbase)
{
  int e = blockIdx.x * 256 + threadIdx.x;
  if (e >= W_TOTAL) return;
  float x;
  if (e < W_PW2)      { int l = e - W_PW1; int n = l >> 6; int k = l & 63;  x = pW1[k * 256 + n]; }
  else if (e < W_PW3) { int l = e - W_PW2; int n = l >> 8; int k = l & 255; x = pW2[k * 256 + n]; }
  else if (e < W_OW1) { int l = e - W_PW3; int n = l >> 8; int k = l & 255; x = pW3[k * 128 + n]; }
  else if (e < W_OW2) { int l = e - W_OW1; int n = l >> 6; int k = l & 63;  x = oW1[k * 256 + n]; }
  else if (e < W_OW3) { int l = e - W_OW2; int n = l >> 8; int k = l & 255; x = oW2[k * 256 + n]; }
  else                { int l = e - W_OW3; int n = l >> 8; int k = l & 255; x = oW3[k * 272 + n]; }
  wbase[e] = bf16_rne(x);
}

// ---------------- Kernel 1: fused MLPs, bf16 MFMA, 64 samples x n-half per wave ----------------
// Wave w: nh = w>>1 owns n-columns [nh*NT*16, ...), sq = (w&1)*64 owns samples sq..sq+63
// (4 sample sets q). Per weight fragment: 4 independent MFMAs (one per q).
// D: sample = set base + (lane&15), n = nbase + nt*16 + (lane>>4)*4 + reg.

template<int K, int NT>
__device__ __forceinline__ void gemm4(const unsigned short* __restrict__ Wh,  // pre-offset by nbase*K
                                      const unsigned short* Xh,               // LDS
                                      int s0, int l15, int kb,
                                      f32x4 acc[][4])
{
  #pragma unroll
  for (int nt = 0; nt < NT; ++nt)
    #pragma unroll
    for (int q = 0; q < 4; ++q) acc[nt][q] = (f32x4){0.f, 0.f, 0.f, 0.f};
  const int sw = (l15 & 7) << 3;
  #pragma unroll
  for (int ks = 0; ks < K / 32; ++ks) {
    const int kk = ks * 32 + kb * 8;
    bf16x8 x[4];
    #pragma unroll
    for (int q = 0; q < 4; ++q)
      x[q] = *(const bf16x8*)&Xh[(s0 + q * 16) * K + (kk ^ sw)];
    #pragma unroll
    for (int nt = 0; nt < NT; ++nt) {
      bf16x8 wh = *(const bf16x8*)&Wh[(nt * 16 + l15) * K + kk];
      #pragma unroll
      for (int q = 0; q < 4; ++q)
        acc[nt][q] = __builtin_amdgcn_mfma_f32_16x16x32_bf16(wh, x[q], acc[nt][q], 0, 0, 0);
    }
  }
}

template<int NT>
__device__ __forceinline__ void relu_store4(f32x4 acc[][4], const float* __restrict__ bias,
                                            unsigned short* Xh, int s0, int kb, int nbase)
{
  const int sw = (s0 & 7) << 3;
  #pragma unroll
  for (int nt = 0; nt < NT; ++nt) {
    const int n0 = nbase + nt * 16 + kb * 4;
    float4 b4 = *(const float4*)&bias[n0];
    #pragma unroll
    for (int q = 0; q < 4; ++q) {
      us4 v;
      #pragma unroll
      for (int r = 0; r < 4; ++r)
        v[r] = bf16_rne(fmaxf(acc[nt][q][r] + (&b4.x)[r], 0.f));
      *(us4*)&Xh[(s0 + q * 16) * 256 + (n0 ^ sw)] = v;
    }
  }
}

extern "C" __global__ void __launch_bounds__(256, 2)
k_mlp(const float* __restrict__ s, const float* __restrict__ a_arr,
      const float* __restrict__ pb1, const float* __restrict__ pb2,
      const float* __restrict__ pb3, const float* __restrict__ ob1,
      const float* __restrict__ ob2, const float* __restrict__ ob3,
      const float* __restrict__ a_log_std,
      const unsigned short* __restrict__ wbase,
      const float* __restrict__ oW3raw,
      float* __restrict__ out, float* __restrict__ ws_logtr0)
{
  __shared__ __align__(16) unsigned short ShS[128 * 64];    // 16 KB
  __shared__ __align__(16) unsigned short XhS[128 * 256];   // 64 KB

  const int tid = threadIdx.x;
  const int r0 = blockIdx.x * 128;
  const int w = tid >> 6, lane = tid & 63;
  const int l15 = lane & 15, kb = lane >> 4;
  const int nh = w >> 1;          // n-half
  const int sq = (w & 1) * 64;    // sample base
  const int s0 = sq + l15;

  // ---- stage s -> ShS (bf16, XOR-swizzled rows) ----
  #pragma unroll
  for (int q = 0; q < 8; ++q) {
    int f4 = q * 256 + tid;
    int e = f4 * 4;
    int row = e >> 6, col = e & 63;
    float4 v = *(const float4*)&s[(size_t)(r0 + row) * 64 + col];
    us4 vh;
    #pragma unroll
    for (int r = 0; r < 4; ++r) vh[r] = bf16_rne((&v.x)[r]);
    int cs = col ^ ((row & 7) << 3);
    *(us4*)&ShS[row * 64 + cs] = vh;
  }
  __syncthreads();

  f32x4 acc[8][4];

  // ---- policy MLP ----
  gemm4<64, 8>(wbase + W_PW1 + (nh * 128) * 64, ShS, s0, l15, kb, acc);
  relu_store4<8>(acc, pb1, XhS, s0, kb, nh * 128);
  __syncthreads();
  gemm4<256, 8>(wbase + W_PW2 + (nh * 128) * 256, XhS, s0, l15, kb, acc);
  relu_store4<8>(acc, pb2, XhS, s0, kb, nh * 128);
  __syncthreads();
  gemm4<256, 4>(wbase + W_PW3 + (nh * 64) * 256, XhS, s0, l15, kb, acc);

  // ---- mean -> log_pis: wave covers c in [nh*8, nh*8+8) for its 64 samples ----
  {
    const int a0i = (kb & 1) * 4;
    float ist[4], ct[4];
    #pragma unroll
    for (int r = 0; r < 4; ++r) {
      float th = tanhf(a_log_std[a0i + r]);
      float logstd = -5.0f + 3.5f * (th + 1.0f);
      ist[r] = __expf(-logstd);
      ct[r] = -logstd - 0.91893853320467274f;  // -logstd - 0.5*log(2pi)
    }
    #pragma unroll
    for (int q = 0; q < 4; ++q) {
      const int t = r0 + sq + q * 16 + l15;
      float4 av = *(const float4*)&a_arr[(size_t)t * 8 + a0i];
      #pragma unroll
      for (int nt = 0; nt < 4; ++nt) {
        float4 b4 = *(const float4*)&pb3[nh * 64 + nt * 16 + kb * 4];
        float s4 = 0.f;
        #pragma unroll
        for (int r = 0; r < 4; ++r) {
          float m = fminf(fmaxf(acc[nt][q][r] + (&b4.x)[r], -10.f), 10.f);
          float z = ((&av.x)[r] - m) * ist[r];
          s4 += fmaf(-0.5f * z, z, ct[r]);
        }
        s4 += __shfl_xor(s4, 16);   // partner kb^1 holds the other 4 a-dims
        if (!(kb & 1)) {
          const int c = nh * 8 + nt * 2 + (kb >> 1);
          out[OFF_PIS + (size_t)t * 16 + c] = s4;
        }
      }
    }
  }
  __syncthreads();

  // ---- option MLP ----
  gemm4<64, 8>(wbase + W_OW1 + (nh * 128) * 64, ShS, s0, l15, kb, acc);
  relu_store4<8>(acc, ob1, XhS, s0, kb, nh * 128);
  __syncthreads();
  gemm4<256, 8>(wbase + W_OW2 + (nh * 128) * 256, XhS, s0, l15, kb, acc);
  relu_store4<8>(acc, ob2, XhS, s0, kb, nh * 128);
  __syncthreads();
  gemm4<256, 8>(wbase + W_OW3 + (nh * 128) * 256, XhS, s0, l15, kb, acc);

  // ---- fused row log_softmax + entropy -> log_trs / entropy (t >= 1) ----
  // Wave covers logits rows [nh*8, nh*8+8) for its 64 samples.
  #pragma unroll
  for (int nt = 0; nt < 8; ++nt) {
    const int row = nh * 8 + nt;
    const int n0 = nh * 128 + nt * 16 + kb * 4;
    float4 b4 = *(const float4*)&ob3[n0];
    #pragma unroll
    for (int q = 0; q < 4; ++q) {
      const int t = r0 + sq + q * 16 + l15;
      float v0 = acc[nt][q][0] + b4.x, v1 = acc[nt][q][1] + b4.y;
      float v2 = acc[nt][q][2] + b4.z, v3 = acc[nt][q][3] + b4.w;
      float mx = fmaxf(fmaxf(v0, v1), fmaxf(v2, v3));
      mx = fmaxf(mx, __shfl_xor(mx, 16));
      mx = fmaxf(mx, __shfl_xor(mx, 32));
      float e0 = __expf(v0 - mx), e1 = __expf(v1 - mx);
      float e2 = __expf(v2 - mx), e3 = __expf(v3 - mx);
      float sm = e0 + e1 + e2 + e3;
      sm += __shfl_xor(sm, 16);
      sm += __shfl_xor(sm, 32);
      float ls = mx + __logf(sm), inv = 1.0f / sm;
      float g0 = v0 - ls, g1 = v1 - ls, g2 = v2 - ls, g3 = v3 - ls;
      float ent = g0 * e0 + g1 * e1 + g2 * e2 + g3 * e3;
      ent += __shfl_xor(ent, 16);
      ent += __shfl_xor(ent, 32);
      if (t >= 1) {
        *(float4*)&out[OFF_TRS + (size_t)(t - 1) * 256 + row * 16 + kb * 4] =
            make_float4(g0, g1, g2, g3);
        if (kb == 0) out[OFF_ENT + (size_t)(t - 1) * 16 + row] = -ent * inv;
      }
    }
  }

  // ---- t=0 logits row 16 (cols 256..271): fp32 dot from LDS X (sample 0) ----
  if (blockIdx.x == 0 && tid < 16) {
    float s0a = 0.f, s1a = 0.f, s2a = 0.f, s3a = 0.f;
    for (int k2 = 0; k2 < 256; k2 += 4) {
      s0a = fmaf(bf16_f(XhS[k2 + 0]), oW3raw[(size_t)(k2 + 0) * 272 + 256 + tid], s0a);
      s1a = fmaf(bf16_f(XhS[k2 + 1]), oW3raw[(size_t)(k2 + 1) * 272 + 256 + tid], s1a);
      s2a = fmaf(bf16_f(XhS[k2 + 2]), oW3raw[(size_t)(k2 + 2) * 272 + 256 + tid], s2a);
      s3a = fmaf(bf16_f(XhS[k2 + 3]), oW3raw[(size_t)(k2 + 3) * 272 + 256 + tid], s3a);
    }
    ws_logtr0[tid] = (s0a + s1a) + (s2a + s3a) + ob3[256 + tid];
  }
}

// ---------------- Kernel 2: chunk fold, 4 parallel sub-chains + in-block combine ----------------
extern "C" __global__ void __launch_bounds__(1024)
k_chunk(const float* __restrict__ out, float* __restrict__ Ms)
{
  __shared__ float Msh[2][4][256];
  __shared__ float Gsh[2][4][256];
  __shared__ float Sub[4][256];
  __shared__ float Pc[2][256];

  const int c = blockIdx.x, tid = threadIdx.x;
  const int group = tid >> 8, gtid = tid & 255;
  const int i = gtid >> 4, j = gtid & 15;
  const int kend = min(c * CLEN + CLEN, NK);
  const int ks0 = c * CLEN + group * SUBL;
  const int ksend = min(ks0 + SUBL, kend);
  const float* trs = out + OFF_TRS;
  const float* pis = out + OFF_PIS;

  float mij = trs[(size_t)ks0 * 256 + gtid] + pis[(size_t)(ks0 + 1) * 16 + j];
  float trp = 0.f, pip = 0.f;
  if (ks0 + 1 < ksend) {
    trp = trs[(size_t)(ks0 + 1) * 256 + gtid];
    pip = pis[(size_t)(ks0 + 2) * 16 + j];
  }
  for (int it = 1; it < SUBL; ++it) {
    const int k = ks0 + it;
    const bool act = k < ksend;                 // group-uniform
    const float graw = trp + pip;               // G[k] (garbage if !act)
    const int kn = k + 1;
    if (kn < ksend) {                           // 1-deep prefetch
      trp = trs[(size_t)kn * 256 + gtid];
      pip = pis[(size_t)(kn + 1) * 16 + j];
    }
    const int sel = it & 1;
    Msh[sel][group][gtid] = mij;
    Gsh[sel][group][gtid] = graw;
    __syncthreads();
    if (act) {
      float tq[16];
      #pragma unroll
      for (int q = 0; q < 16; ++q) tq[q] = Msh[sel][group][i * 16 + q] + Gsh[sel][group][q * 16 + j];
      float mx = tq[0];
      #pragma unroll
      for (int q = 1; q < 16; ++q) mx = fmaxf(mx, tq[q]);
      float ssum = 0.f;
      #pragma unroll
      for (int q = 0; q < 16; ++q) ssum += __expf(tq[q] - mx);
      mij = mx + __logf(ssum);
    }
  }

  Sub[group][gtid] = mij;
  __syncthreads();
  if (group < 2) {
    const float* A = Sub[group * 2];
    const float* B = Sub[group * 2 + 1];
    float tq[16];
    #pragma unroll
    for (int q = 0; q < 16; ++q) tq[q] = A[i * 16 + q] + B[q * 16 + j];
    float mx = tq[0];
    #pragma unroll
    for (int q = 1; q < 16; ++q) mx = fmaxf(mx, tq[q]);
    float ssum = 0.f;
    #pragma unroll
    for (int q = 0; q < 16; ++q) ssum += __expf(tq[q] - mx);
    Pc[group][gtid] = mx + __logf(ssum);
  }
  __syncthreads();
  if (group == 0) {
    float tq[16];
    #pragma unroll
    for (int q = 0; q < 16; ++q) tq[q] = Pc[0][i * 16 + q] + Pc[1][q * 16 + j];
    float mx = tq[0];
    #pragma unroll
    for (int q = 1; q < 16; ++q) mx = fmaxf(mx, tq[q]);
    float ssum = 0.f;
    #pragma unroll
    for (int q = 0; q < 16; ++q) ssum += __expf(tq[q] - mx);
    Ms[c * 256 + gtid] = mx + __logf(ssum);
  }
}

// ---------------- Kernel 3: boundary scan (1 wave per direction), 4-slot prefetch ----------------
extern "C" __global__ void __launch_bounds__(64)
k_boundary(const float* __restrict__ Ms, const float* __restrict__ lt0,
           float* __restrict__ out, float* __restrict__ bA, float* __restrict__ bB)
{
  const int l = threadIdx.x;
  const int g = l >> 4;
  const int j = l & 15;
  if (blockIdx.x == 0) {
    // a0 = log_softmax(lt0) + log_pis[0]
    float ltp = lt0[j];
    float mx = ltp;
    #pragma unroll
    for (int d = 1; d < 16; d <<= 1) mx = fmaxf(mx, __shfl_xor(mx, d));
    float sm = __expf(ltp - mx);
    #pragma unroll
    for (int d = 1; d < 16; d <<= 1) sm += __shfl_xor(sm, d);
    float ls = mx + __logf(sm);
    float a0p = ltp - ls + out[OFF_PIS + j];
    if (l < 16) { bA[l] = a0p; out[OFF_ALPHA + l] = a0p; }
    float v0 = __shfl(a0p, g * 4 + 0), v1 = __shfl(a0p, g * 4 + 1);
    float v2 = __shfl(a0p, g * 4 + 2), v3 = __shfl(a0p, g * 4 + 3);
    float tp[4][4];
    #pragma unroll
    for (int r = 0; r < 4; ++r)
      #pragma unroll
      for (int q = 0; q < 4; ++q)
        tp[r][q] = Ms[r * 256 + (g * 4 + q) * 16 + j];   // M[r][g*4+q][j]
    for (int cb = 0; cb < NCH; cb += 4) {
      #pragma unroll
      for (int u = 0; u < 4; ++u) {
        const int c = cb + u;
        float t0 = v0 + tp[u][0], t1 = v1 + tp[u][1];
        float t2 = v2 + tp[u][2], t3 = v3 + tp[u][3];
        float m = fmaxf(fmaxf(t0, t1), fmaxf(t2, t3));
        float ssum = __expf(t0 - m) + __expf(t1 - m) + __expf(t2 - m) + __expf(t3 - m);
        lse_merge(m, ssum, __shfl_xor(m, 16), __shfl_xor(ssum, 16));
        lse_merge(m, ssum, __shfl_xor(m, 32), __shfl_xor(ssum, 32));
        float nv = m + __logf(ssum);
        if (c + 1 < NCH && l < 16) bA[(c + 1) * 16 + l] = nv;
        v0 = __shfl(nv, g * 4 + 0); v1 = __shfl(nv, g * 4 + 1);
        v2 = __shfl(nv, g * 4 + 2); v3 = __shfl(nv, g * 4 + 3);
        const int cn = c + 4;
        if (cn < NCH) {
          #pragma unroll
          for (int q = 0; q < 4; ++q)
            tp[u][q] = Ms[cn * 256 + (g * 4 + q) * 16 + j];
        }
      }
    }
  } else {
    const int i = j;
    float w0 = 0.f, w1 = 0.f, w2 = 0.f, w3 = 0.f;
    if (l < 16) {
      bB[(NCH - 1) * 16 + l] = 0.f;
      out[OFF_BETA + (size_t)(TT - 1) * 16 + l] = 0.f;
    }
    float4 sl[4];
    #pragma unroll
    for (int r = 0; r < 4; ++r)
      sl[r] = *(const float4*)&Ms[(NCH - 1 - r) * 256 + i * 16 + g * 4];
    for (int cb = NCH - 1; cb >= 0; cb -= 4) {
      #pragma unroll
      for (int u = 0; u < 4; ++u) {
        const int c = cb - u;
        float4 mr = sl[u];
        float t0 = w0 + mr.x, t1 = w1 + mr.y, t2 = w2 + mr.z, t3 = w3 + mr.w;
        float m = fmaxf(fmaxf(t0, t1), fmaxf(t2, t3));
        float ssum = __expf(t0 - m) + __expf(t1 - m) + __expf(t2 - m) + __expf(t3 - m);
        lse_merge(m, ssum, __shfl_xor(m, 16), __shfl_xor(ssum, 16));
        lse_merge(m, ssum, __shfl_xor(m, 32), __shfl_xor(ssum, 32));
        float nw = m + __logf(ssum);
        if (c > 0 && l < 16) bB[(c - 1) * 16 + l] = nw;
        w0 = __shfl(nw, g * 4 + 0); w1 = __shfl(nw, g * 4 + 1);
        w2 = __shfl(nw, g * 4 + 2); w3 = __shfl(nw, g * 4 + 3);
        const int cn = c - 4;
        if (cn >= 0) sl[u] = *(const float4*)&Ms[cn * 256 + i * 16 + g * 4];
      }
    }
  }
}

// ---------------- Kernel 4: per-chunk replay, depth-8 rolling register prefetch ----------------
#define PD 8
extern "C" __global__ void __launch_bounds__(64)
k_replay(float* __restrict__ out, const float* __restrict__ bA, const float* __restrict__ bB)
{
  const int l = threadIdx.x;
  const int g = l >> 4;
  const float* trs = out + OFF_TRS;
  const float* pis = out + OFF_PIS;
  if (blockIdx.x < NCH) {
    const int c = blockIdx.x;
    const int k0 = c * CLEN, k1 = min(k0 + CLEN, NK) - 1;
    const int j = l & 15;
    float v0 = bA[c * 16 + g * 4 + 0], v1 = bA[c * 16 + g * 4 + 1];
    float v2 = bA[c * 16 + g * 4 + 2], v3 = bA[c * 16 + g * 4 + 3];
    float tp[PD][4];
    float pp[PD];
    #pragma unroll
    for (int r = 0; r < PD; ++r) {
      const int kk = min(k0 + r, k1);
      #pragma unroll
      for (int q = 0; q < 4; ++q) tp[r][q] = trs[(size_t)kk * 256 + (g * 4 + q) * 16 + j];
      pp[r] = pis[(size_t)(kk + 1) * 16 + j];
    }
    for (int kb2 = k0; kb2 <= k1; kb2 += PD) {
      #pragma unroll
      for (int u = 0; u < PD; ++u) {
        const int k = kb2 + u;
        if (k <= k1) {
          float t0 = v0 + tp[u][0], t1 = v1 + tp[u][1];
          float t2 = v2 + tp[u][2], t3 = v3 + tp[u][3];
          float m = fmaxf(fmaxf(t0, t1), fmaxf(t2, t3));
          float ssum = __expf(t0 - m) + __expf(t1 - m) + __expf(t2 - m) + __expf(t3 - m);
          lse_merge(m, ssum, __shfl_xor(m, 16), __shfl_xor(ssum, 16));
          lse_merge(m, ssum, __shfl_xor(m, 32), __shfl_xor(ssum, 32));
          float nv = m + __logf(ssum) + pp[u];
          if (l < 16) out[OFF_ALPHA + (size_t)(k + 1) * 16 + l] = nv;
          v0 = __shfl(nv, g * 4 + 0); v1 = __shfl(nv, g * 4 + 1);
          v2 = __shfl(nv, g * 4 + 2); v3 = __shfl(nv, g * 4 + 3);
          const int kn = k + PD;
          if (kn <= k1) {
            #pragma unroll
            for (int q = 0; q < 4; ++q) tp[u][q] = trs[(size_t)kn * 256 + (g * 4 + q) * 16 + j];
            pp[u] = pis[(size_t)(kn + 1) * 16 + j];
          }
        }
      }
    }
  } else {
    const int c = blockIdx.x - NCH;
    const int k0 = c * CLEN, k1 = min(k0 + CLEN, NK) - 1;
    const int i = l & 15;
    float w0 = bB[c * 16 + g * 4 + 0], w1 = bB[c * 16 + g * 4 + 1];
    float w2 = bB[c * 16 + g * 4 + 2], w3 = bB[c * 16 + g * 4 + 3];
    float4 t4[PD];
    float4 p4[PD];
    #pragma unroll
    for (int r = 0; r < PD; ++r) {
      const int kk = max(k1 - r, k0);
      t4[r] = *(const float4*)&trs[(size_t)kk * 256 + i * 16 + g * 4];
      p4[r] = *(const float4*)&pis[(size_t)(kk + 1) * 16 + g * 4];
    }
    for (int kb2 = k1; kb2 >= k0; kb2 -= PD) {
      #pragma unroll
      for (int u = 0; u < PD; ++u) {
        const int k = kb2 - u;
        if (k >= k0) {
          float t0 = w0 + t4[u].x + p4[u].x;
          float t1 = w1 + t4[u].y + p4[u].y;
          float t2 = w2 + t4[u].z + p4[u].z;
          float t3 = w3 + t4[u].w + p4[u].w;
          float m = fmaxf(fmaxf(t0, t1), fmaxf(t2, t3));
          float ssum = __expf(t0 - m) + __expf(t1 - m) + __expf(t2 - m) + __expf(t3 - m);
          lse_merge(m, ssum, __shfl_xor(m, 16), __shfl_xor(ssum, 16));
          lse_merge(m, ssum, __shfl_xor(m, 32), __shfl_xor(ssum, 32));
          float nw = m + __logf(ssum);
          if (l < 16) out[OFF_BETA + (size_t)k * 16 + l] = nw;
          w0 = __shfl(nw, g * 4 + 0); w1 = __shfl(nw, g * 4 + 1);
          w2 = __shfl(nw, g * 4 + 2); w3 = __shfl(nw, g * 4 + 3);
          const int kn = k - PD;
          if (kn >= k0) {
            t4[u] = *(const float4*)&trs[(size_t)kn * 256 + i * 16 + g * 4];
            p4[u] = *(const float4*)&pis[(size_t)(kn + 1) * 16 + g * 4];
          }
        }
      }
    }
  }
}

extern "C" void kernel_launch(void* const* d_in, const int* in_sizes, int n_in,
                              void* d_out, int out_size, void* d_ws, size_t ws_size,
                              hipStream_t stream)
{
  const float* s     = (const float*)d_in[0];
  const float* a_arr = (const float*)d_in[1];
  const float* pW1 = (const float*)d_in[2];
  const float* pb1 = (const float*)d_in[3];
  const float* pW2 = (const float*)d_in[4];
  const float* pb2 = (const float*)d_in[5];
  const float* pW3 = (const float*)d_in[6];
  const float* pb3 = (const float*)d_in[7];
  const float* oW1 = (const float*)d_in[8];
  const float* ob1 = (const float*)d_in[9];
  const float* oW2 = (const float*)d_in[10];
  const float* ob2 = (const float*)d_in[11];
  const float* oW3 = (const float*)d_in[12];
  const float* ob3 = (const float*)d_in[13];
  const float* a_log_std = (const float*)d_in[14];
  float* out = (float*)d_out;

  // ws float region: Ms[131072] | bA[8192] | bB[8192] | lt0[16]  -> weights after
  float* wsf = (float*)d_ws;
  float* Ms  = wsf;
  float* bA  = wsf + 131072;
  float* bB  = wsf + 139264;
  float* lt0 = wsf + 147456;
  unsigned short* wbase = (unsigned short*)((char*)d_ws + WS_WEIGHT_OFF);

  k_wconv<<<(W_TOTAL + 255) / 256, 256, 0, stream>>>(pW1, pW2, pW3, oW1, oW2, oW3, wbase);
  k_mlp<<<TT / 128, 256, 0, stream>>>(s, a_arr, pb1, pb2, pb3, ob1, ob2, ob3,
                                      a_log_std, wbase, oW3, out, lt0);
  k_chunk<<<NCH, 1024, 0, stream>>>(out, Ms);
  k_boundary<<<2, 64, 0, stream>>>(Ms, lt0, out, bA, bB);
  k_replay<<<2 * NCH, 64, 0, stream>>>(out, bA, bB);
}

// Round 8
// 354.700 us; speedup vs baseline: 1.4841x; 1.4841x over previous
//
#include <hip/hip_runtime.h>
#include <cstddef>

// Problem dims
#define TT 65536
#define NK (TT - 1)      // scan steps
#define NCH 512          // chunks
#define CLEN 128         // chunk length
#define SUBL 32          // sub-chain length inside k_chunk (CLEN/4)
#define NSUP 32          // super-chunks (NCH/16)

// d_out offsets (floats): log_alpha, log_beta, log_trs, log_pis, entropy
#define OFF_ALPHA 0
#define OFF_BETA  (TT * 16)
#define OFF_TRS   (2 * TT * 16)
#define OFF_PIS   (OFF_TRS + NK * 256)
#define OFF_ENT   (OFF_PIS + TT * 16)

// bf16 weight plane element offsets (ushort units), layout [n][k]
#define W_PW1 0        // 256 x 64
#define W_PW2 16384    // 256 x 256
#define W_PW3 81920    // 128 x 256
#define W_OW1 114688   // 256 x 64
#define W_OW2 131072   // 256 x 256
#define W_OW3 196608   // 272 x 256 (rows 256..271 unused by MFMA path)
#define W_TOTAL 266240
#define WS_WEIGHT_OFF 626752   // bytes: scan float region sits below this

typedef __attribute__((ext_vector_type(8))) short bf16x8;
typedef __attribute__((ext_vector_type(4))) float f32x4;
typedef __attribute__((ext_vector_type(4))) unsigned short us4;

__device__ __forceinline__ unsigned short bf16_rne(float x) {
  unsigned int u = __float_as_uint(x);
  unsigned int r = u + 0x7FFFu + ((u >> 16) & 1u);
  return (unsigned short)(r >> 16);
}
__device__ __forceinline__ float bf16_f(unsigned short h) {
  return __uint_as_float(((unsigned int)h) << 16);
}

__device__ __forceinline__ void lse_merge(float& m, float& s, float mo, float so) {
  float mm = fmaxf(m, mo);
  s = s * __expf(m - mm) + so * __expf(mo - mm);
  m = mm;
}

// ---------------- Kernel 0: weight convert fp32 -> bf16 hi plane, [n][k] ----------------
extern "C" __global__ void __launch_bounds__(256)
k_wconv(const float* __restrict__ pW1, const float* __restrict__ pW2,
        const float* __restrict__ pW3, const float* __restrict__ oW1,
        const float* __restrict__ oW2, const float* __restrict__ oW3,
        unsigned short* __restrict__ wbase)
{
  int e = blockIdx.x * 256 + threadIdx.x;
  if (e >= W_TOTAL) return;
  float x;
  if (e < W_PW2)      { int l = e - W_PW1; int n = l >> 6; int k = l & 63;  x = pW1[k * 256 + n]; }
  else if (e < W_PW3) { int l = e - W_PW2; int n = l >> 8; int k = l & 255; x = pW2[k * 256 + n]; }
  else if (e < W_OW1) { int l = e - W_PW3; int n = l >> 8; int k = l & 255; x = pW3[k * 128 + n]; }
  else if (e < W_OW2) { int l = e - W_OW1; int n = l >> 6; int k = l & 63;  x = oW1[k * 256 + n]; }
  else if (e < W_OW3) { int l = e - W_OW2; int n = l >> 8; int k = l & 255; x = oW2[k * 256 + n]; }
  else                { int l = e - W_OW3; int n = l >> 8; int k = l & 255; x = oW3[k * 272 + n]; }
  wbase[e] = bf16_rne(x);
}

// ---------------- Kernel 1: fused MLPs, bf16 MFMA, 64 samples x n-half per wave ----------------
template<int K, int NT>
__device__ __forceinline__ void gemm4(const unsigned short* __restrict__ Wh,  // pre-offset by nbase*K
                                      const unsigned short* Xh,               // LDS
                                      int s0, int l15, int kb,
                                      f32x4 acc[][4])
{
  #pragma unroll
  for (int nt = 0; nt < NT; ++nt)
    #pragma unroll
    for (int q = 0; q < 4; ++q) acc[nt][q] = (f32x4){0.f, 0.f, 0.f, 0.f};
  const int sw = (l15 & 7) << 3;
  #pragma unroll
  for (int ks = 0; ks < K / 32; ++ks) {
    const int kk = ks * 32 + kb * 8;
    bf16x8 x[4];
    #pragma unroll
    for (int q = 0; q < 4; ++q)
      x[q] = *(const bf16x8*)&Xh[(s0 + q * 16) * K + (kk ^ sw)];
    #pragma unroll
    for (int nt = 0; nt < NT; ++nt) {
      bf16x8 wh = *(const bf16x8*)&Wh[(nt * 16 + l15) * K + kk];
      #pragma unroll
      for (int q = 0; q < 4; ++q)
        acc[nt][q] = __builtin_amdgcn_mfma_f32_16x16x32_bf16(wh, x[q], acc[nt][q], 0, 0, 0);
    }
  }
}

template<int NT>
__device__ __forceinline__ void relu_store4(f32x4 acc[][4], const float* __restrict__ bias,
                                            unsigned short* Xh, int s0, int kb, int nbase)
{
  const int sw = (s0 & 7) << 3;
  #pragma unroll
  for (int nt = 0; nt < NT; ++nt) {
    const int n0 = nbase + nt * 16 + kb * 4;
    float4 b4 = *(const float4*)&bias[n0];
    #pragma unroll
    for (int q = 0; q < 4; ++q) {
      us4 v;
      #pragma unroll
      for (int r = 0; r < 4; ++r)
        v[r] = bf16_rne(fmaxf(acc[nt][q][r] + (&b4.x)[r], 0.f));
      *(us4*)&Xh[(s0 + q * 16) * 256 + (n0 ^ sw)] = v;
    }
  }
}

extern "C" __global__ void __launch_bounds__(256, 2)
k_mlp(const float* __restrict__ s, const float* __restrict__ a_arr,
      const float* __restrict__ pb1, const float* __restrict__ pb2,
      const float* __restrict__ pb3, const float* __restrict__ ob1,
      const float* __restrict__ ob2, const float* __restrict__ ob3,
      const float* __restrict__ a_log_std,
      const unsigned short* __restrict__ wbase,
      const float* __restrict__ oW3raw,
      float* __restrict__ out, float* __restrict__ ws_logtr0)
{
  __shared__ __align__(16) unsigned short ShS[128 * 64];    // 16 KB
  __shared__ __align__(16) unsigned short XhS[128 * 256];   // 64 KB

  const int tid = threadIdx.x;
  const int r0 = blockIdx.x * 128;
  const int w = tid >> 6, lane = tid & 63;
  const int l15 = lane & 15, kb = lane >> 4;
  const int nh = w >> 1;          // n-half
  const int sq = (w & 1) * 64;    // sample base
  const int s0 = sq + l15;

  // ---- stage s -> ShS (bf16, XOR-swizzled rows) ----
  #pragma unroll
  for (int q = 0; q < 8; ++q) {
    int f4 = q * 256 + tid;
    int e = f4 * 4;
    int row = e >> 6, col = e & 63;
    float4 v = *(const float4*)&s[(size_t)(r0 + row) * 64 + col];
    us4 vh;
    #pragma unroll
    for (int r = 0; r < 4; ++r) vh[r] = bf16_rne((&v.x)[r]);
    int cs = col ^ ((row & 7) << 3);
    *(us4*)&ShS[row * 64 + cs] = vh;
  }
  __syncthreads();

  f32x4 acc[8][4];

  // ---- policy MLP ----
  gemm4<64, 8>(wbase + W_PW1 + (nh * 128) * 64, ShS, s0, l15, kb, acc);
  relu_store4<8>(acc, pb1, XhS, s0, kb, nh * 128);
  __syncthreads();
  gemm4<256, 8>(wbase + W_PW2 + (nh * 128) * 256, XhS, s0, l15, kb, acc);
  relu_store4<8>(acc, pb2, XhS, s0, kb, nh * 128);
  __syncthreads();
  gemm4<256, 4>(wbase + W_PW3 + (nh * 64) * 256, XhS, s0, l15, kb, acc);

  // ---- mean -> log_pis: wave covers c in [nh*8, nh*8+8) for its 64 samples ----
  {
    const int a0i = (kb & 1) * 4;
    float ist[4], ct[4];
    #pragma unroll
    for (int r = 0; r < 4; ++r) {
      float th = tanhf(a_log_std[a0i + r]);
      float logstd = -5.0f + 3.5f * (th + 1.0f);
      ist[r] = __expf(-logstd);
      ct[r] = -logstd - 0.91893853320467274f;  // -logstd - 0.5*log(2pi)
    }
    #pragma unroll
    for (int q = 0; q < 4; ++q) {
      const int t = r0 + sq + q * 16 + l15;
      float4 av = *(const float4*)&a_arr[(size_t)t * 8 + a0i];
      #pragma unroll
      for (int nt = 0; nt < 4; ++nt) {
        float4 b4 = *(const float4*)&pb3[nh * 64 + nt * 16 + kb * 4];
        float s4 = 0.f;
        #pragma unroll
        for (int r = 0; r < 4; ++r) {
          float m = fminf(fmaxf(acc[nt][q][r] + (&b4.x)[r], -10.f), 10.f);
          float z = ((&av.x)[r] - m) * ist[r];
          s4 += fmaf(-0.5f * z, z, ct[r]);
        }
        s4 += __shfl_xor(s4, 16);   // partner kb^1 holds the other 4 a-dims
        if (!(kb & 1)) {
          const int c = nh * 8 + nt * 2 + (kb >> 1);
          out[OFF_PIS + (size_t)t * 16 + c] = s4;
        }
      }
    }
  }
  __syncthreads();

  // ---- option MLP ----
  gemm4<64, 8>(wbase + W_OW1 + (nh * 128) * 64, ShS, s0, l15, kb, acc);
  relu_store4<8>(acc, ob1, XhS, s0, kb, nh * 128);
  __syncthreads();
  gemm4<256, 8>(wbase + W_OW2 + (nh * 128) * 256, XhS, s0, l15, kb, acc);
  relu_store4<8>(acc, ob2, XhS, s0, kb, nh * 128);
  __syncthreads();
  gemm4<256, 8>(wbase + W_OW3 + (nh * 128) * 256, XhS, s0, l15, kb, acc);

  // ---- fused row log_softmax + entropy -> log_trs / entropy (t >= 1) ----
  #pragma unroll
  for (int nt = 0; nt < 8; ++nt) {
    const int row = nh * 8 + nt;
    const int n0 = nh * 128 + nt * 16 + kb * 4;
    float4 b4 = *(const float4*)&ob3[n0];
    #pragma unroll
    for (int q = 0; q < 4; ++q) {
      const int t = r0 + sq + q * 16 + l15;
      float v0 = acc[nt][q][0] + b4.x, v1 = acc[nt][q][1] + b4.y;
      float v2 = acc[nt][q][2] + b4.z, v3 = acc[nt][q][3] + b4.w;
      float mx = fmaxf(fmaxf(v0, v1), fmaxf(v2, v3));
      mx = fmaxf(mx, __shfl_xor(mx, 16));
      mx = fmaxf(mx, __shfl_xor(mx, 32));
      float e0 = __expf(v0 - mx), e1 = __expf(v1 - mx);
      float e2 = __expf(v2 - mx), e3 = __expf(v3 - mx);
      float sm = e0 + e1 + e2 + e3;
      sm += __shfl_xor(sm, 16);
      sm += __shfl_xor(sm, 32);
      float ls = mx + __logf(sm), inv = 1.0f / sm;
      float g0 = v0 - ls, g1 = v1 - ls, g2 = v2 - ls, g3 = v3 - ls;
      float ent = g0 * e0 + g1 * e1 + g2 * e2 + g3 * e3;
      ent += __shfl_xor(ent, 16);
      ent += __shfl_xor(ent, 32);
      if (t >= 1) {
        *(float4*)&out[OFF_TRS + (size_t)(t - 1) * 256 + row * 16 + kb * 4] =
            make_float4(g0, g1, g2, g3);
        if (kb == 0) out[OFF_ENT + (size_t)(t - 1) * 16 + row] = -ent * inv;
      }
    }
  }

  // ---- t=0 logits row 16 (cols 256..271): fp32 dot from LDS X (sample 0) ----
  if (blockIdx.x == 0 && tid < 16) {
    float s0a = 0.f, s1a = 0.f, s2a = 0.f, s3a = 0.f;
    for (int k2 = 0; k2 < 256; k2 += 4) {
      s0a = fmaf(bf16_f(XhS[k2 + 0]), oW3raw[(size_t)(k2 + 0) * 272 + 256 + tid], s0a);
      s1a = fmaf(bf16_f(XhS[k2 + 1]), oW3raw[(size_t)(k2 + 1) * 272 + 256 + tid], s1a);
      s2a = fmaf(bf16_f(XhS[k2 + 2]), oW3raw[(size_t)(k2 + 2) * 272 + 256 + tid], s2a);
      s3a = fmaf(bf16_f(XhS[k2 + 3]), oW3raw[(size_t)(k2 + 3) * 272 + 256 + tid], s3a);
    }
    ws_logtr0[tid] = (s0a + s1a) + (s2a + s3a) + ob3[256 + tid];
  }
}

// ---------------- Kernel 2: chunk fold, 4 parallel sub-chains + in-block combine ----------------
extern "C" __global__ void __launch_bounds__(1024)
k_chunk(const float* __restrict__ out, float* __restrict__ Ms)
{
  __shared__ float Msh[2][4][256];
  __shared__ float Gsh[2][4][256];
  __shared__ float Sub[4][256];
  __shared__ float Pc[2][256];

  const int c = blockIdx.x, tid = threadIdx.x;
  const int group = tid >> 8, gtid = tid & 255;
  const int i = gtid >> 4, j = gtid & 15;
  const int kend = min(c * CLEN + CLEN, NK);
  const int ks0 = c * CLEN + group * SUBL;
  const int ksend = min(ks0 + SUBL, kend);
  const float* trs = out + OFF_TRS;
  const float* pis = out + OFF_PIS;

  float mij = trs[(size_t)ks0 * 256 + gtid] + pis[(size_t)(ks0 + 1) * 16 + j];
  float trp = 0.f, pip = 0.f;
  if (ks0 + 1 < ksend) {
    trp = trs[(size_t)(ks0 + 1) * 256 + gtid];
    pip = pis[(size_t)(ks0 + 2) * 16 + j];
  }
  for (int it = 1; it < SUBL; ++it) {
    const int k = ks0 + it;
    const bool act = k < ksend;                 // group-uniform
    const float graw = trp + pip;               // G[k] (garbage if !act)
    const int kn = k + 1;
    if (kn < ksend) {                           // 1-deep prefetch
      trp = trs[(size_t)kn * 256 + gtid];
      pip = pis[(size_t)(kn + 1) * 16 + j];
    }
    const int sel = it & 1;
    Msh[sel][group][gtid] = mij;
    Gsh[sel][group][gtid] = graw;
    __syncthreads();
    if (act) {
      float tq[16];
      #pragma unroll
      for (int q = 0; q < 16; ++q) tq[q] = Msh[sel][group][i * 16 + q] + Gsh[sel][group][q * 16 + j];
      float mx = tq[0];
      #pragma unroll
      for (int q = 1; q < 16; ++q) mx = fmaxf(mx, tq[q]);
      float ssum = 0.f;
      #pragma unroll
      for (int q = 0; q < 16; ++q) ssum += __expf(tq[q] - mx);
      mij = mx + __logf(ssum);
    }
  }

  Sub[group][gtid] = mij;
  __syncthreads();
  if (group < 2) {
    const float* A = Sub[group * 2];
    const float* B = Sub[group * 2 + 1];
    float tq[16];
    #pragma unroll
    for (int q = 0; q < 16; ++q) tq[q] = A[i * 16 + q] + B[q * 16 + j];
    float mx = tq[0];
    #pragma unroll
    for (int q = 1; q < 16; ++q) mx = fmaxf(mx, tq[q]);
    float ssum = 0.f;
    #pragma unroll
    for (int q = 0; q < 16; ++q) ssum += __expf(tq[q] - mx);
    Pc[group][gtid] = mx + __logf(ssum);
  }
  __syncthreads();
  if (group == 0) {
    float tq[16];
    #pragma unroll
    for (int q = 0; q < 16; ++q) tq[q] = Pc[0][i * 16 + q] + Pc[1][q * 16 + j];
    float mx = tq[0];
    #pragma unroll
    for (int q = 1; q < 16; ++q) mx = fmaxf(mx, tq[q]);
    float ssum = 0.f;
    #pragma unroll
    for (int q = 0; q < 16; ++q) ssum += __expf(tq[q] - mx);
    Ms[c * 256 + gtid] = mx + __logf(ssum);
  }
}

// ---------------- Kernel 2b: fold 16 chunk matrices -> 1 super matrix ----------------
extern "C" __global__ void __launch_bounds__(256)
k_super(const float* __restrict__ Ms, float* __restrict__ Sup)
{
  __shared__ float A[2][256];
  __shared__ float B[2][256];
  const int g = blockIdx.x, tid = threadIdx.x;
  const int i = tid >> 4, j = tid & 15;
  const int c0 = g * 16;
  float mij = Ms[(size_t)c0 * 256 + tid];
  float gn = Ms[(size_t)(c0 + 1) * 256 + tid];
  for (int t = 1; t < 16; ++t) {
    const int sel = t & 1;
    A[sel][tid] = mij;
    B[sel][tid] = gn;
    __syncthreads();
    if (t + 1 < 16) gn = Ms[(size_t)(c0 + t + 1) * 256 + tid];
    float tq[16];
    #pragma unroll
    for (int q = 0; q < 16; ++q) tq[q] = A[sel][i * 16 + q] + B[sel][q * 16 + j];
    float mx = tq[0];
    #pragma unroll
    for (int q = 1; q < 16; ++q) mx = fmaxf(mx, tq[q]);
    float ssum = 0.f;
    #pragma unroll
    for (int q = 0; q < 16; ++q) ssum += __expf(tq[q] - mx);
    mij = mx + __logf(ssum);
  }
  Sup[(size_t)g * 256 + tid] = mij;
}

// ---------------- Kernel 3a: top boundary scan over 32 super matrices ----------------
extern "C" __global__ void __launch_bounds__(64)
k_btop(const float* __restrict__ Sup, const float* __restrict__ lt0,
       float* __restrict__ out, float* __restrict__ vSupA, float* __restrict__ wSupB)
{
  __shared__ float S[NSUP][272];   // stride-17 rows: 16*17=272
  const int l = threadIdx.x;
  for (int e = l; e < NSUP * 256; e += 64) {
    int m = e >> 8, r = (e >> 4) & 15, cc = e & 15;
    S[m][r * 17 + cc] = Sup[e];
  }
  __syncthreads();
  const int gg = l >> 4, j = l & 15;
  if (blockIdx.x == 0) {
    // a0 = log_softmax(lt0) + log_pis[0]
    float ltp = lt0[j];
    float mx = ltp;
    #pragma unroll
    for (int d = 1; d < 16; d <<= 1) mx = fmaxf(mx, __shfl_xor(mx, d));
    float sm = __expf(ltp - mx);
    #pragma unroll
    for (int d = 1; d < 16; d <<= 1) sm += __shfl_xor(sm, d);
    float ls = mx + __logf(sm);
    float vown = ltp - ls + out[OFF_PIS + j];
    if (l < 16) out[OFF_ALPHA + l] = vown;
    float v0 = __shfl(vown, gg * 4 + 0), v1 = __shfl(vown, gg * 4 + 1);
    float v2 = __shfl(vown, gg * 4 + 2), v3 = __shfl(vown, gg * 4 + 3);
    for (int g2 = 0; g2 < NSUP; ++g2) {
      if (l < 16) vSupA[g2 * 16 + l] = vown;
      float t0 = v0 + S[g2][(gg * 4 + 0) * 17 + j];
      float t1 = v1 + S[g2][(gg * 4 + 1) * 17 + j];
      float t2 = v2 + S[g2][(gg * 4 + 2) * 17 + j];
      float t3 = v3 + S[g2][(gg * 4 + 3) * 17 + j];
      float m = fmaxf(fmaxf(t0, t1), fmaxf(t2, t3));
      float ssum = __expf(t0 - m) + __expf(t1 - m) + __expf(t2 - m) + __expf(t3 - m);
      lse_merge(m, ssum, __shfl_xor(m, 16), __shfl_xor(ssum, 16));
      lse_merge(m, ssum, __shfl_xor(m, 32), __shfl_xor(ssum, 32));
      vown = m + __logf(ssum);
      v0 = __shfl(vown, gg * 4 + 0); v1 = __shfl(vown, gg * 4 + 1);
      v2 = __shfl(vown, gg * 4 + 2); v3 = __shfl(vown, gg * 4 + 3);
    }
  } else {
    float wown = 0.f;
    if (l < 16) out[OFF_BETA + (size_t)(TT - 1) * 16 + l] = 0.f;
    float w0 = 0.f, w1 = 0.f, w2 = 0.f, w3 = 0.f;
    for (int g2 = NSUP - 1; g2 >= 0; --g2) {
      if (l < 16) wSupB[g2 * 16 + l] = wown;
      float t0 = w0 + S[g2][j * 17 + gg * 4 + 0];
      float t1 = w1 + S[g2][j * 17 + gg * 4 + 1];
      float t2 = w2 + S[g2][j * 17 + gg * 4 + 2];
      float t3 = w3 + S[g2][j * 17 + gg * 4 + 3];
      float m = fmaxf(fmaxf(t0, t1), fmaxf(t2, t3));
      float ssum = __expf(t0 - m) + __expf(t1 - m) + __expf(t2 - m) + __expf(t3 - m);
      lse_merge(m, ssum, __shfl_xor(m, 16), __shfl_xor(ssum, 16));
      lse_merge(m, ssum, __shfl_xor(m, 32), __shfl_xor(ssum, 32));
      wown = m + __logf(ssum);
      w0 = __shfl(wown, gg * 4 + 0); w1 = __shfl(wown, gg * 4 + 1);
      w2 = __shfl(wown, gg * 4 + 2); w3 = __shfl(wown, gg * 4 + 3);
    }
  }
}

// ---------------- Kernel 3b: mid boundary scan, 16 chunks per super (parallel) ----------------
extern "C" __global__ void __launch_bounds__(64)
k_bmid(const float* __restrict__ Ms, const float* __restrict__ vSupA,
       const float* __restrict__ wSupB, float* __restrict__ bA, float* __restrict__ bB)
{
  __shared__ float S[16][272];
  const int l = threadIdx.x;
  const bool alpha = blockIdx.x < NSUP;
  const int g = alpha ? blockIdx.x : blockIdx.x - NSUP;
  const int c0 = g * 16;
  for (int e = l; e < 16 * 256; e += 64) {
    int m = e >> 8, r = (e >> 4) & 15, cc = e & 15;
    S[m][r * 17 + cc] = Ms[(size_t)c0 * 256 + e];
  }
  __syncthreads();
  const int gg = l >> 4, j = l & 15;
  if (alpha) {
    float vown = vSupA[g * 16 + j];
    float v0 = __shfl(vown, gg * 4 + 0), v1 = __shfl(vown, gg * 4 + 1);
    float v2 = __shfl(vown, gg * 4 + 2), v3 = __shfl(vown, gg * 4 + 3);
    for (int t = 0; t < 16; ++t) {
      if (l < 16) bA[(c0 + t) * 16 + l] = vown;
      if (t == 15) break;
      float t0 = v0 + S[t][(gg * 4 + 0) * 17 + j];
      float t1 = v1 + S[t][(gg * 4 + 1) * 17 + j];
      float t2 = v2 + S[t][(gg * 4 + 2) * 17 + j];
      float t3 = v3 + S[t][(gg * 4 + 3) * 17 + j];
      float m = fmaxf(fmaxf(t0, t1), fmaxf(t2, t3));
      float ssum = __expf(t0 - m) + __expf(t1 - m) + __expf(t2 - m) + __expf(t3 - m);
      lse_merge(m, ssum, __shfl_xor(m, 16), __shfl_xor(ssum, 16));
      lse_merge(m, ssum, __shfl_xor(m, 32), __shfl_xor(ssum, 32));
      vown = m + __logf(ssum);
      v0 = __shfl(vown, gg * 4 + 0); v1 = __shfl(vown, gg * 4 + 1);
      v2 = __shfl(vown, gg * 4 + 2); v3 = __shfl(vown, gg * 4 + 3);
    }
  } else {
    float wown = wSupB[g * 16 + j];
    float w0 = __shfl(wown, gg * 4 + 0), w1 = __shfl(wown, gg * 4 + 1);
    float w2 = __shfl(wown, gg * 4 + 2), w3 = __shfl(wown, gg * 4 + 3);
    for (int t = 15; t >= 0; --t) {
      if (l < 16) bB[(c0 + t) * 16 + l] = wown;
      if (t == 0) break;
      float t0 = w0 + S[t][j * 17 + gg * 4 + 0];
      float t1 = w1 + S[t][j * 17 + gg * 4 + 1];
      float t2 = w2 + S[t][j * 17 + gg * 4 + 2];
      float t3 = w3 + S[t][j * 17 + gg * 4 + 3];
      float m = fmaxf(fmaxf(t0, t1), fmaxf(t2, t3));
      float ssum = __expf(t0 - m) + __expf(t1 - m) + __expf(t2 - m) + __expf(t3 - m);
      lse_merge(m, ssum, __shfl_xor(m, 16), __shfl_xor(ssum, 16));
      lse_merge(m, ssum, __shfl_xor(m, 32), __shfl_xor(ssum, 32));
      wown = m + __logf(ssum);
      w0 = __shfl(wown, gg * 4 + 0); w1 = __shfl(wown, gg * 4 + 1);
      w2 = __shfl(wown, gg * 4 + 2); w3 = __shfl(wown, gg * 4 + 3);
    }
  }
}

// ---------------- Kernel 4: per-chunk replay, depth-8 rolling register prefetch ----------------
#define PD 8
extern "C" __global__ void __launch_bounds__(64)
k_replay(float* __restrict__ out, const float* __restrict__ bA, const float* __restrict__ bB)
{
  const int l = threadIdx.x;
  const int g = l >> 4;
  const float* trs = out + OFF_TRS;
  const float* pis = out + OFF_PIS;
  if (blockIdx.x < NCH) {
    const int c = blockIdx.x;
    const int k0 = c * CLEN, k1 = min(k0 + CLEN, NK) - 1;
    const int j = l & 15;
    float v0 = bA[c * 16 + g * 4 + 0], v1 = bA[c * 16 + g * 4 + 1];
    float v2 = bA[c * 16 + g * 4 + 2], v3 = bA[c * 16 + g * 4 + 3];
    float tp[PD][4];
    float pp[PD];
    #pragma unroll
    for (int r = 0; r < PD; ++r) {
      const int kk = min(k0 + r, k1);
      #pragma unroll
      for (int q = 0; q < 4; ++q) tp[r][q] = trs[(size_t)kk * 256 + (g * 4 + q) * 16 + j];
      pp[r] = pis[(size_t)(kk + 1) * 16 + j];
    }
    for (int kb2 = k0; kb2 <= k1; kb2 += PD) {
      #pragma unroll
      for (int u = 0; u < PD; ++u) {
        const int k = kb2 + u;
        if (k <= k1) {
          float t0 = v0 + tp[u][0], t1 = v1 + tp[u][1];
          float t2 = v2 + tp[u][2], t3 = v3 + tp[u][3];
          float m = fmaxf(fmaxf(t0, t1), fmaxf(t2, t3));
          float ssum = __expf(t0 - m) + __expf(t1 - m) + __expf(t2 - m) + __expf(t3 - m);
          lse_merge(m, ssum, __shfl_xor(m, 16), __shfl_xor(ssum, 16));
          lse_merge(m, ssum, __shfl_xor(m, 32), __shfl_xor(ssum, 32));
          float nv = m + __logf(ssum) + pp[u];
          if (l < 16) out[OFF_ALPHA + (size_t)(k + 1) * 16 + l] = nv;
          v0 = __shfl(nv, g * 4 + 0); v1 = __shfl(nv, g * 4 + 1);
          v2 = __shfl(nv, g * 4 + 2); v3 = __shfl(nv, g * 4 + 3);
          const int kn = k + PD;
          if (kn <= k1) {
            #pragma unroll
            for (int q = 0; q < 4; ++q) tp[u][q] = trs[(size_t)kn * 256 + (g * 4 + q) * 16 + j];
            pp[u] = pis[(size_t)(kn + 1) * 16 + j];
          }
        }
      }
    }
  } else {
    const int c = blockIdx.x - NCH;
    const int k0 = c * CLEN, k1 = min(k0 + CLEN, NK) - 1;
    const int i = l & 15;
    float w0 = bB[c * 16 + g * 4 + 0], w1 = bB[c * 16 + g * 4 + 1];
    float w2 = bB[c * 16 + g * 4 + 2], w3 = bB[c * 16 + g * 4 + 3];
    float4 t4[PD];
    float4 p4[PD];
    #pragma unroll
    for (int r = 0; r < PD; ++r) {
      const int kk = max(k1 - r, k0);
      t4[r] = *(const float4*)&trs[(size_t)kk * 256 + i * 16 + g * 4];
      p4[r] = *(const float4*)&pis[(size_t)(kk + 1) * 16 + g * 4];
    }
    for (int kb2 = k1; kb2 >= k0; kb2 -= PD) {
      #pragma unroll
      for (int u = 0; u < PD; ++u) {
        const int k = kb2 - u;
        if (k >= k0) {
          float t0 = w0 + t4[u].x + p4[u].x;
          float t1 = w1 + t4[u].y + p4[u].y;
          float t2 = w2 + t4[u].z + p4[u].z;
          float t3 = w3 + t4[u].w + p4[u].w;
          float m = fmaxf(fmaxf(t0, t1), fmaxf(t2, t3));
          float ssum = __expf(t0 - m) + __expf(t1 - m) + __expf(t2 - m) + __expf(t3 - m);
          lse_merge(m, ssum, __shfl_xor(m, 16), __shfl_xor(ssum, 16));
          lse_merge(m, ssum, __shfl_xor(m, 32), __shfl_xor(ssum, 32));
          float nw = m + __logf(ssum);
          if (l < 16) out[OFF_BETA + (size_t)k * 16 + l] = nw;
          w0 = __shfl(nw, g * 4 + 0); w1 = __shfl(nw, g * 4 + 1);
          w2 = __shfl(nw, g * 4 + 2); w3 = __shfl(nw, g * 4 + 3);
          const int kn = k - PD;
          if (kn >= k0) {
            t4[u] = *(const float4*)&trs[(size_t)kn * 256 + i * 16 + g * 4];
            p4[u] = *(const float4*)&pis[(size_t)(kn + 1) * 16 + g * 4];
          }
        }
      }
    }
  }
}

extern "C" void kernel_launch(void* const* d_in, const int* in_sizes, int n_in,
                              void* d_out, int out_size, void* d_ws, size_t ws_size,
                              hipStream_t stream)
{
  const float* s     = (const float*)d_in[0];
  const float* a_arr = (const float*)d_in[1];
  const float* pW1 = (const float*)d_in[2];
  const float* pb1 = (const float*)d_in[3];
  const float* pW2 = (const float*)d_in[4];
  const float* pb2 = (const float*)d_in[5];
  const float* pW3 = (const float*)d_in[6];
  const float* pb3 = (const float*)d_in[7];
  const float* oW1 = (const float*)d_in[8];
  const float* ob1 = (const float*)d_in[9];
  const float* oW2 = (const float*)d_in[10];
  const float* ob2 = (const float*)d_in[11];
  const float* oW3 = (const float*)d_in[12];
  const float* ob3 = (const float*)d_in[13];
  const float* a_log_std = (const float*)d_in[14];
  float* out = (float*)d_out;

  // ws float region:
  // Ms[131072] | bA[8192] | bB[8192] | lt0[16] | Sup[8192] | vSupA[512] | wSupB[512]
  float* wsf = (float*)d_ws;
  float* Ms    = wsf;
  float* bA    = wsf + 131072;
  float* bB    = wsf + 139264;
  float* lt0   = wsf + 147456;
  float* Sup   = wsf + 147472;
  float* vSupA = wsf + 155664;
  float* wSupB = wsf + 156176;
  unsigned short* wbase = (unsigned short*)((char*)d_ws + WS_WEIGHT_OFF);

  k_wconv<<<(W_TOTAL + 255) / 256, 256, 0, stream>>>(pW1, pW2, pW3, oW1, oW2, oW3, wbase);
  k_mlp<<<TT / 128, 256, 0, stream>>>(s, a_arr, pb1, pb2, pb3, ob1, ob2, ob3,
                                      a_log_std, wbase, oW3, out, lt0);
  k_chunk<<<NCH, 1024, 0, stream>>>(out, Ms);
  k_super<<<NSUP, 256, 0, stream>>>(Ms, Sup);
  k_btop<<<2, 64, 0, stream>>>(Sup, lt0, out, vSupA, wSupB);
  k_bmid<<<2 * NSUP, 64, 0, stream>>>(Ms, vSupA, wSupB, bA, bB);
  k_replay<<<2 * NCH, 64, 0, stream>>>(out, bA, bB);
}